// Round 2
// baseline (206.237 us; speedup 1.0000x reference)
//
#include <hip/hip_runtime.h>
#include <hip/hip_bf16.h>

#define NN 256
#define HH 256
#define DD 64

// Workspace layout (floats). Total 100352 floats = 401,408 bytes.
//  P  [256][64]   @ 0        P[i][d] = act[i]·Wd[0:2,d] + goal[i]·Wd[2:4,d] + b_dist[d]
//  Q  [256][64]   @ 16384    Q[j][d] = act[j]·Wd[4:6,d] + goal[j]·Wd[6:8,d]
//  T  [256][256]  @ 32768    T[j][h] = tanh(ahs[j][h])
//  WA [4][256]    @ 98304    WA[z][h] = sum_f wm[z][h][f] * a_flat[256+f]
//  WB [4][256]    @ 99328    WB[z][h] = sum_f wm[z][h][f] * a_flat[f]

__global__ __launch_bounds__(256) void precompute_kernel(
    const float* __restrict__ ahs, const float* __restrict__ goal,
    const float* __restrict__ action, const float* __restrict__ Wd,
    const float* __restrict__ b_dist, const float* __restrict__ w,
    const float* __restrict__ a, float* __restrict__ ws)
{
    const int b = blockIdx.x;
    const int t = threadIdx.x;
    float* P  = ws;
    float* Q  = ws + 16384;
    float* T  = ws + 32768;
    float* WA = ws + 98304;
    float* WB = ws + 99328;
    if (b < NN) {
        T[b*HH + t] = tanhf(ahs[b*HH + t]);
        if (t < DD) {
            float a0 = action[2*b], a1 = action[2*b+1];
            float g0 = goal[2*b],   g1 = goal[2*b+1];
            P[b*DD + t] = a0*Wd[0*DD+t] + a1*Wd[1*DD+t]
                        + g0*Wd[2*DD+t] + g1*Wd[3*DD+t] + b_dist[t];
            Q[b*DD + t] = a0*Wd[4*DD+t] + a1*Wd[5*DD+t]
                        + g0*Wd[6*DD+t] + g1*Wd[7*DD+t];
        }
    } else {
        int r = b - NN;            // 0..7: 0-3 -> WA, 4-7 -> WB
        int z = r & 3;
        const float* wrow = w + z*HH*HH + t*HH;
        const float* av   = a + ((r < 4) ? HH : 0);
        float acc = 0.f;
        for (int f = 0; f < HH; ++f) acc = fmaf(wrow[f], av[f], acc);
        if (r < 4) WA[z*HH + t] = acc; else WB[z*HH + t] = acc;
    }
}

// One block per row n. Threads t=0..255; thread t owns hidden-column h=t.
// Online softmax over k (k=0 self + 256 neighbors), j processed in chunks of 32.
__global__ __launch_bounds__(256) void gat_row_kernel(
    const float* __restrict__ ahs, const float* __restrict__ ghs,
    const float* __restrict__ Wg,  const float* __restrict__ b_gate,
    const float* __restrict__ w,   const float* __restrict__ bias,
    const float* __restrict__ ws,  float* __restrict__ out)
{
    const int n    = blockIdx.x;
    const int t    = threadIdx.x;
    const int wid  = t >> 6;   // wave id == head z
    const int lane = t & 63;

    const float* P  = ws;
    const float* Q  = ws + 16384;
    const float* T  = ws + 32768;
    const float* WA = ws + 98304;
    const float* WB = ws + 99328;

    __shared__ float hid[32][64];       // relu(P[n]+Q[j]) chunk
    __shared__ float gac[32][257];      // gated values chunk (pad 257: conflict-free col writes + row reads)
    __shared__ float vacc[4][256];      // online-softmax numerator per head
    __shared__ float wa_s[4][256];
    __shared__ float alpha_s[4][32];
    __shared__ float m_s[4], l_s[4], scl_s[4], cz_s[4];

    // per-thread preloads
    float wg[64];
#pragma unroll
    for (int d = 0; d < 64; ++d) wg[d] = Wg[d*HH + t];   // W_gate column t
    const float bg     = b_gate[t];
    const float ahs_nt = ahs[n*HH + t];

#pragma unroll
    for (int z = 0; z < 4; ++z) {
        wa_s[z][t] = WA[z*HH + t];
        vacc[z][t] = ahs_nt;          // k=0 term: h_other[n,0] = ahs[n], weight exp(e0-m)=1
    }

    const int jj_own = t >> 3;
    const int db     = (t & 7) * 8;
    float pn[8];
#pragma unroll
    for (int i = 0; i < 8; ++i) pn[i] = P[n*DD + db + i];

    __syncthreads();

    // init online softmax with k=0; wave `wid` handles head z=wid
    {
        float pc = 0.f, ps = 0.f;
        for (int h = lane; h < HH; h += 64) {
            float av = ahs[n*HH + h];
            pc = fmaf(av, WB[wid*HH + h], pc);
            ps = fmaf(av, wa_s[wid][h], ps);
        }
#pragma unroll
        for (int off = 32; off; off >>= 1) {
            pc += __shfl_xor(pc, off);
            ps += __shfl_xor(ps, off);
        }
        if (lane == 0) {
            float sc = pc + ps;                     // score[z,n,0]
            float e0 = sc > 0.f ? sc : 0.2f * sc;   // leaky relu
            cz_s[wid] = pc;                          // common term c[z,n]
            m_s[wid]  = e0;
            l_s[wid]  = 1.0f;
        }
    }
    __syncthreads();

    for (int cc = 0; cc < 8; ++cc) {
        const int j0 = cc * 32;

        // step 1: hidden chunk = relu(P[n] + Q[j])
        {
            const int j = j0 + jj_own;
            const float4 qa = *(const float4*)(Q + j*DD + db);
            const float4 qb = *(const float4*)(Q + j*DD + db + 4);
            float4 ha, hb;
            ha.x = fmaxf(pn[0] + qa.x, 0.f); ha.y = fmaxf(pn[1] + qa.y, 0.f);
            ha.z = fmaxf(pn[2] + qa.z, 0.f); ha.w = fmaxf(pn[3] + qa.w, 0.f);
            hb.x = fmaxf(pn[4] + qb.x, 0.f); hb.y = fmaxf(pn[5] + qb.y, 0.f);
            hb.z = fmaxf(pn[6] + qb.z, 0.f); hb.w = fmaxf(pn[7] + qb.w, 0.f);
            *(float4*)&hid[jj_own][db]   = ha;
            *(float4*)&hid[jj_own][db+4] = hb;
        }
        __syncthreads();

        // step 2: gate MLP 64->1 per (j, h=t); gated value into LDS
        for (int jj = 0; jj < 32; ++jj) {
            const int j = j0 + jj;
            float u = bg;
            const float4* hp = (const float4*)(&hid[jj][0]);
#pragma unroll
            for (int q = 0; q < 16; ++q) {
                float4 hv = hp[q];
                u = fmaf(hv.x, wg[4*q+0], u);
                u = fmaf(hv.y, wg[4*q+1], u);
                u = fmaf(hv.z, wg[4*q+2], u);
                u = fmaf(hv.w, wg[4*q+3], u);
            }
            float val;
            if (j == n) {                       // diagonal: goal_hidden_state (block-uniform branch)
                val = ghs[j*HH + t];
            } else {
                float g = 1.0f / (1.0f + __expf(-u));
                val = g * T[j*HH + t];
            }
            gac[jj][t] = val;
        }
        __syncthreads();

        // step 3: scores + online softmax update (wave wid = head z)
        {
            const int jj    = lane & 31;
            const int hbase = (lane >> 5) * 128;
            const float* gr  = &gac[jj][hbase];
            const float* war = &wa_s[wid][hbase];
            float partial = 0.f;
#pragma unroll 8
            for (int hh = 0; hh < 128; ++hh) partial = fmaf(gr[hh], war[hh], partial);
            partial += __shfl_down(partial, 32);   // lanes 0..31 hold full sums

            float e = -INFINITY;
            if (lane < 32) {
                float sc = cz_s[wid] + partial;
                e = sc > 0.f ? sc : 0.2f * sc;
            }
            float mx = e;
#pragma unroll
            for (int off = 32; off; off >>= 1) mx = fmaxf(mx, __shfl_xor(mx, off));
            float m_old = m_s[wid];
            float m_new = fmaxf(m_old, mx);
            float at = (lane < 32) ? __expf(e - m_new) : 0.f;
            float ssum = at;
#pragma unroll
            for (int off = 32; off; off >>= 1) ssum += __shfl_xor(ssum, off);
            if (lane < 32) alpha_s[wid][jj] = at;
            if (lane == 0) {
                float scale = __expf(m_old - m_new);
                scl_s[wid] = scale;
                l_s[wid]   = l_s[wid]*scale + ssum;
                m_s[wid]   = m_new;
            }
        }
        __syncthreads();

        // step 4: accumulate v[z][t]
        {
            float v0 = vacc[0][t]*scl_s[0];
            float v1 = vacc[1][t]*scl_s[1];
            float v2 = vacc[2][t]*scl_s[2];
            float v3 = vacc[3][t]*scl_s[3];
            for (int jj = 0; jj < 32; ++jj) {
                float g = gac[jj][t];
                v0 = fmaf(alpha_s[0][jj], g, v0);
                v1 = fmaf(alpha_s[1][jj], g, v1);
                v2 = fmaf(alpha_s[2][jj], g, v2);
                v3 = fmaf(alpha_s[3][jj], g, v3);
            }
            vacc[0][t] = v0; vacc[1][t] = v1; vacc[2][t] = v2; vacc[3][t] = v3;
        }
        __syncthreads();
    }

    // final: out[n,f=t] = relu( 1/4 * sum_z (1/l_z) * sum_h v[z,h] * wm[z,h,f] ) + bias[f]
    {
        float res = 0.f;
#pragma unroll
        for (int z = 0; z < 4; ++z) {
            float az = 0.f;
            const float* wz = w + z*HH*HH + t;          // column f=t, stride HH
            const float4* vp = (const float4*)(&vacc[z][0]);
            for (int h4 = 0; h4 < 64; ++h4) {
                float4 v4 = vp[h4];
                az = fmaf(v4.x, wz[(4*h4+0)*HH], az);
                az = fmaf(v4.y, wz[(4*h4+1)*HH], az);
                az = fmaf(v4.z, wz[(4*h4+2)*HH], az);
                az = fmaf(v4.w, wz[(4*h4+3)*HH], az);
            }
            res += az / l_s[z];
        }
        res *= 0.25f;
        res = fmaxf(res, 0.f) + bias[t];
        out[n*HH + t] = res;
    }
}

extern "C" void kernel_launch(void* const* d_in, const int* in_sizes, int n_in,
                              void* d_out, int out_size, void* d_ws, size_t ws_size,
                              hipStream_t stream)
{
    const float* ahs    = (const float*)d_in[0];
    const float* ghs    = (const float*)d_in[1];
    const float* goal   = (const float*)d_in[2];
    const float* action = (const float*)d_in[3];
    const float* Wd     = (const float*)d_in[4];
    const float* b_dist = (const float*)d_in[5];
    const float* Wg     = (const float*)d_in[6];
    const float* b_gate = (const float*)d_in[7];
    const float* w      = (const float*)d_in[8];
    const float* a      = (const float*)d_in[9];
    const float* bias   = (const float*)d_in[10];
    float* ws  = (float*)d_ws;     // needs 401,408 bytes
    float* outp = (float*)d_out;

    precompute_kernel<<<264, 256, 0, stream>>>(ahs, goal, action, Wd, b_dist, w, a, ws);
    gat_row_kernel<<<256, 256, 0, stream>>>(ahs, ghs, Wg, b_gate, w, bias, ws, outp);
}

// Round 4
// 163.111 us; speedup vs baseline: 1.2644x; 1.2644x over previous
//
#include <hip/hip_runtime.h>
#include <hip/hip_bf16.h>

#define NN 256
#define HH 256

typedef __attribute__((ext_vector_type(8))) short short8;
typedef __attribute__((ext_vector_type(4))) float f32x4;

__device__ __forceinline__ ushort f2bf(float x) {
    __hip_bfloat16 h = __float2bfloat16(x);
    return *reinterpret_cast<ushort*>(&h);
}
// 16-lane row sum-reduction stage (DPP on the VALU pipe, no LDS).
// ctrl must be a compile-time constant -> template parameter.
// xor1: quad_perm(1,0,3,2)=0xB1; xor2: quad_perm(2,3,0,1)=0x4E;
// 4-group swap: row_half_mirror=0x141; 8-group swap: row_mirror=0x140.
template <int CTRL>
__device__ __forceinline__ float dpp_add(float x) {
    int y = __builtin_amdgcn_update_dpp(0, __float_as_int(x), CTRL, 0xF, 0xF, true);
    return x + __int_as_float(y);
}
__device__ __forceinline__ float red16(float v) {
    v = dpp_add<0xB1>(v);
    v = dpp_add<0x4E>(v);
    v = dpp_add<0x141>(v);
    v = dpp_add<0x140>(v);
    return v;
}

// Workspace (floats): P[256][64]@0  Q[256][64]@16384  T[256][256]@32768
//                     WA[4][256]@98304  WB[4][256]@99328
//                     WgT bf16[256][64] (as ushort) @ float-offset 100352
// total 108544 floats = 434,176 bytes

__global__ __launch_bounds__(256) void precompute_kernel(
    const float* __restrict__ ahs, const float* __restrict__ goal,
    const float* __restrict__ action, const float* __restrict__ Wd,
    const float* __restrict__ b_dist, const float* __restrict__ Wg,
    const float* __restrict__ w, const float* __restrict__ a,
    float* __restrict__ ws)
{
    const int b = blockIdx.x;
    const int t = threadIdx.x;
    float* P  = ws;
    float* Q  = ws + 16384;
    float* T  = ws + 32768;
    float* WA = ws + 98304;
    float* WB = ws + 99328;
    ushort* WgT = (ushort*)(ws + 100352);

    if (b < NN) {
        T[b*HH + t] = tanhf(ahs[b*HH + t]);
        if (t < 64) {
            float a0 = action[2*b], a1 = action[2*b+1];
            float g0 = goal[2*b],   g1 = goal[2*b+1];
            P[b*64 + t] = a0*Wd[0*64+t] + a1*Wd[1*64+t]
                        + g0*Wd[2*64+t] + g1*Wd[3*64+t] + b_dist[t];
            Q[b*64 + t] = a0*Wd[4*64+t] + a1*Wd[5*64+t]
                        + g0*Wd[6*64+t] + g1*Wd[7*64+t];
        }
    } else if (b < NN + 8) {
        // WA/WB: 256-dot per thread, float4 + 4 accumulators (break dep chain)
        int r = b - NN;
        int z = r & 3;
        const float* wrow = w + z*HH*HH + t*HH;
        const float* av   = a + ((r < 4) ? HH : 0);
        float a0=0.f, a1=0.f, a2=0.f, a3=0.f;
        for (int f = 0; f < HH; f += 4) {
            a0 = fmaf(wrow[f+0], av[f+0], a0);
            a1 = fmaf(wrow[f+1], av[f+1], a1);
            a2 = fmaf(wrow[f+2], av[f+2], a2);
            a3 = fmaf(wrow[f+3], av[f+3], a3);
        }
        float acc = (a0+a1)+(a2+a3);
        if (r < 4) WA[z*HH + t] = acc; else WB[z*HH + t] = acc;
    } else {
        // WgT[h][d] = bf16(Wg[d][h])  (B-operand layout for MFMA: K-major per row h)
        for (int d = 0; d < 64; ++d) WgT[t*64 + d] = f2bf(Wg[d*HH + t]);
    }
}

// One block per row n; 4 waves; wave wid owns h-stripe [wid*64, wid*64+64).
// Per 32-j chunk: MFMA computes U=Hid@Wg; vals stay in registers through
// score partials (DPP-reduced), softmax (cross-wave via tiny LDS), and
// alpha-weighted accumulation. No value tile ever round-trips through LDS.
__global__ __launch_bounds__(256) void gat_row_kernel(
    const float* __restrict__ ahs, const float* __restrict__ ghs,
    const float* __restrict__ b_gate, const float* __restrict__ w,
    const float* __restrict__ bias, const float* __restrict__ ws,
    float* __restrict__ out)
{
    const int n    = blockIdx.x;
    const int t    = threadIdx.x;
    const int wid  = t >> 6;      // wave id == also head z for softmax bookkeeping
    const int lane = t & 63;
    const int quad = lane >> 4;
    const int l15  = lane & 15;
    const int n0   = wid * 64;

    const float* P  = ws;
    const float* Q  = ws + 16384;
    const float* T  = ws + 32768;
    const float* WA = ws + 98304;
    const float* WB = ws + 99328;
    const ushort* WgT = (const ushort*)(ws + 100352);

    __shared__ ushort hidb[32][72];                    // bf16 hid chunk, padded row (144 B)
    __shared__ __align__(16) float part[4][32][4];     // score partials [z][j][wave]
    __shared__ __align__(16) float alpha_s[32][4];     // alpha [j][z]
    __shared__ __align__(16) float scl4[4];
    __shared__ float m_s[4], l_s[4], cz_s[4];
    __shared__ float vred[4][4][260];                  // [quad][z][h] partial vacc
    __shared__ float vfin[4][256];

    // per-lane h columns (4 per lane, one per n-tile)
    int hcol[4];
#pragma unroll
    for (int nt = 0; nt < 4; ++nt) hcol[nt] = n0 + nt*16 + l15;

    // hoisted B-fragments (Wg), wa, b_gate, per-lane
    short8 bfrag[4][2];
    float  wa_reg[4][4];   // [z][nt]
    float  bgv[4];
#pragma unroll
    for (int nt = 0; nt < 4; ++nt) {
#pragma unroll
        for (int kh = 0; kh < 2; ++kh)
            bfrag[nt][kh] = *(const short8*)(WgT + hcol[nt]*64 + kh*32 + quad*8);
#pragma unroll
        for (int z = 0; z < 4; ++z) wa_reg[z][nt] = WA[z*HH + hcol[nt]];
        bgv[nt] = b_gate[hcol[nt]];
    }

    // vacc in registers: [z][nt]; k=0 self term (val=ahs) carried by quad 0 only
    float vacc[4][4];
    {
        float av[4];
#pragma unroll
        for (int nt = 0; nt < 4; ++nt) av[nt] = ahs[n*HH + hcol[nt]];
#pragma unroll
        for (int z = 0; z < 4; ++z)
#pragma unroll
            for (int nt = 0; nt < 4; ++nt)
                vacc[z][nt] = (quad == 0) ? av[nt] : 0.f;
    }

    // step-1 assignment: thread owns row jj_own, cols [db, db+8)
    const int jj_own = t >> 3;
    const int db     = (t & 7) * 8;
    float pn[8];
#pragma unroll
    for (int i = 0; i < 8; ++i) pn[i] = P[n*64 + db + i];

    // init online softmax with k=0 (wave wid handles head z=wid)
    {
        float pc = 0.f, ps = 0.f;
        for (int h = lane; h < HH; h += 64) {
            float av = ahs[n*HH + h];
            pc = fmaf(av, WB[wid*HH + h], pc);
            ps = fmaf(av, WA[wid*HH + h], ps);
        }
#pragma unroll
        for (int off = 32; off; off >>= 1) {
            pc += __shfl_xor(pc, off);
            ps += __shfl_xor(ps, off);
        }
        if (lane == 0) {
            float sc = pc + ps;
            float e0 = sc > 0.f ? sc : 0.2f * sc;
            cz_s[wid] = pc;
            m_s[wid]  = e0;
            l_s[wid]  = 1.0f;
        }
    }
    __syncthreads();

    for (int cc = 0; cc < 8; ++cc) {
        const int j0 = cc * 32;

        // ---- s1: hid chunk = relu(P[n]+Q[j]) -> bf16 LDS ----
        {
            const int j = j0 + jj_own;
            const float4 qa = *(const float4*)(Q + j*64 + db);
            const float4 qb = *(const float4*)(Q + j*64 + db + 4);
            ushort hv[8];
            hv[0] = f2bf(fmaxf(pn[0] + qa.x, 0.f));
            hv[1] = f2bf(fmaxf(pn[1] + qa.y, 0.f));
            hv[2] = f2bf(fmaxf(pn[2] + qa.z, 0.f));
            hv[3] = f2bf(fmaxf(pn[3] + qa.w, 0.f));
            hv[4] = f2bf(fmaxf(pn[4] + qb.x, 0.f));
            hv[5] = f2bf(fmaxf(pn[5] + qb.y, 0.f));
            hv[6] = f2bf(fmaxf(pn[6] + qb.z, 0.f));
            hv[7] = f2bf(fmaxf(pn[7] + qb.w, 0.f));
            *(short8*)&hidb[jj_own][db] = *(short8*)hv;
        }
        __syncthreads();   // B1

        // ---- s2: MFMA U = Hid @ Wg, epilogue in regs ----
        f32x4 acc[2][4];
#pragma unroll
        for (int mt = 0; mt < 2; ++mt)
#pragma unroll
            for (int nt = 0; nt < 4; ++nt) acc[mt][nt] = (f32x4){0.f,0.f,0.f,0.f};

        short8 afrag[2][2];
#pragma unroll
        for (int mt = 0; mt < 2; ++mt)
#pragma unroll
            for (int kh = 0; kh < 2; ++kh)
                afrag[mt][kh] = *(const short8*)&hidb[mt*16 + l15][kh*32 + quad*8];

#pragma unroll
        for (int mt = 0; mt < 2; ++mt)
#pragma unroll
            for (int nt = 0; nt < 4; ++nt) {
                acc[mt][nt] = __builtin_amdgcn_mfma_f32_16x16x32_bf16(
                    afrag[mt][0], bfrag[nt][0], acc[mt][nt], 0, 0, 0);
                acc[mt][nt] = __builtin_amdgcn_mfma_f32_16x16x32_bf16(
                    afrag[mt][1], bfrag[nt][1], acc[mt][nt], 0, 0, 0);
            }

        // epilogue: gate -> val (regs), fused score partials
        float vals[2][4][4];     // [mt][nt][r]
        float pp[4][2][4];       // [z][mt][r]
#pragma unroll
        for (int z = 0; z < 4; ++z)
#pragma unroll
            for (int mt = 0; mt < 2; ++mt)
#pragma unroll
                for (int r = 0; r < 4; ++r) pp[z][mt][r] = 0.f;

#pragma unroll
        for (int mt = 0; mt < 2; ++mt) {
#pragma unroll
            for (int r = 0; r < 4; ++r) {
                const int jg = j0 + mt*16 + quad*4 + r;   // D-layout: row=(lane>>4)*4+r
                const bool diag = (jg == n);
#pragma unroll
                for (int nt = 0; nt < 4; ++nt) {
                    float u = acc[mt][nt][r] + bgv[nt];
                    float val;
                    if (diag) {
                        val = ghs[n*HH + hcol[nt]];
                    } else {
                        float g = 1.0f / (1.0f + __expf(-u));
                        val = g * T[jg*HH + hcol[nt]];
                    }
                    vals[mt][nt][r] = val;
                    pp[0][mt][r] = fmaf(val, wa_reg[0][nt], pp[0][mt][r]);
                    pp[1][mt][r] = fmaf(val, wa_reg[1][nt], pp[1][mt][r]);
                    pp[2][mt][r] = fmaf(val, wa_reg[2][nt], pp[2][mt][r]);
                    pp[3][mt][r] = fmaf(val, wa_reg[3][nt], pp[3][mt][r]);
                }
            }
        }
        // reduce partials across the 16 lanes sharing each row (DPP, VALU pipe)
#pragma unroll
        for (int z = 0; z < 4; ++z)
#pragma unroll
            for (int mt = 0; mt < 2; ++mt)
#pragma unroll
                for (int r = 0; r < 4; ++r)
                    pp[z][mt][r] = red16(pp[z][mt][r]);
        if (l15 == 0) {
#pragma unroll
            for (int z = 0; z < 4; ++z)
#pragma unroll
                for (int mt = 0; mt < 2; ++mt)
#pragma unroll
                    for (int r = 0; r < 4; ++r)
                        part[z][mt*16 + quad*4 + r][wid] = pp[z][mt][r];
        }
        __syncthreads();   // B2

        // ---- s3: softmax update for head z=wid ----
        {
            const int jj = lane & 31;
            f32x4 pr = *(const f32x4*)&part[wid][jj][0];
            const bool act = lane < 32;
            float s = cz_s[wid] + ((pr.x + pr.y) + (pr.z + pr.w));
            float e = act ? (s > 0.f ? s : 0.2f * s) : -__builtin_inff();
            float mx = e;
#pragma unroll
            for (int off = 32; off; off >>= 1) mx = fmaxf(mx, __shfl_xor(mx, off));
            float m_old = m_s[wid];
            float m_new = fmaxf(m_old, mx);
            float at = act ? __expf(e - m_new) : 0.f;
            float ss = at;
#pragma unroll
            for (int off = 32; off; off >>= 1) ss += __shfl_xor(ss, off);
            if (act) alpha_s[jj][wid] = at;
            if (lane == 0) {
                float scale = __expf(m_old - m_new);
                scl4[wid] = scale;
                l_s[wid]  = l_s[wid] * scale + ss;
                m_s[wid]  = m_new;
            }
        }
        __syncthreads();   // B3

        // ---- s4: vacc update, all in registers ----
        {
            f32x4 scv = *(const f32x4*)&scl4[0];
            float s0 = scv.x, s1 = scv.y, s2 = scv.z, s3 = scv.w;
#pragma unroll
            for (int nt = 0; nt < 4; ++nt) {
                vacc[0][nt] *= s0; vacc[1][nt] *= s1;
                vacc[2][nt] *= s2; vacc[3][nt] *= s3;
            }
#pragma unroll
            for (int mt = 0; mt < 2; ++mt)
#pragma unroll
                for (int r = 0; r < 4; ++r) {
                    f32x4 al = *(const f32x4*)&alpha_s[mt*16 + quad*4 + r][0];
#pragma unroll
                    for (int nt = 0; nt < 4; ++nt) {
                        float v = vals[mt][nt][r];
                        vacc[0][nt] = fmaf(al.x, v, vacc[0][nt]);
                        vacc[1][nt] = fmaf(al.y, v, vacc[1][nt]);
                        vacc[2][nt] = fmaf(al.z, v, vacc[2][nt]);
                        vacc[3][nt] = fmaf(al.w, v, vacc[3][nt]);
                    }
                }
        }
        // no barrier needed here: next chunk's part/alpha writes are separated by B1'/B2'
    }

    // reduce vacc over quads via LDS, divide by l, project through w
#pragma unroll
    for (int z = 0; z < 4; ++z)
#pragma unroll
        for (int nt = 0; nt < 4; ++nt)
            vred[quad][z][hcol[nt]] = vacc[z][nt];
    __syncthreads();
#pragma unroll
    for (int z = 0; z < 4; ++z)
        vfin[z][t] = (vred[0][z][t] + vred[1][z][t] + vred[2][z][t] + vred[3][z][t]) / l_s[z];
    __syncthreads();

    {
        float res = 0.f;
#pragma unroll
        for (int z = 0; z < 4; ++z) {
            const float* wz = w + z*HH*HH + t;     // column f=t, stride HH
            const f32x4* vp = (const f32x4*)&vfin[z][0];
            float az0 = 0.f, az1 = 0.f;
            for (int h4 = 0; h4 < 64; ++h4) {
                f32x4 v4 = vp[h4];
                az0 = fmaf(v4.x, wz[(4*h4+0)*HH], az0);
                az1 = fmaf(v4.y, wz[(4*h4+1)*HH], az1);
                az0 = fmaf(v4.z, wz[(4*h4+2)*HH], az0);
                az1 = fmaf(v4.w, wz[(4*h4+3)*HH], az1);
            }
            res += az0 + az1;
        }
        res = fmaxf(res * 0.25f, 0.f) + bias[t];
        out[n*HH + t] = res;
    }
}

extern "C" void kernel_launch(void* const* d_in, const int* in_sizes, int n_in,
                              void* d_out, int out_size, void* d_ws, size_t ws_size,
                              hipStream_t stream)
{
    const float* ahs    = (const float*)d_in[0];
    const float* ghs    = (const float*)d_in[1];
    const float* goal   = (const float*)d_in[2];
    const float* action = (const float*)d_in[3];
    const float* Wd     = (const float*)d_in[4];
    const float* b_dist = (const float*)d_in[5];
    const float* Wg     = (const float*)d_in[6];
    const float* b_gate = (const float*)d_in[7];
    const float* w      = (const float*)d_in[8];
    const float* a      = (const float*)d_in[9];
    const float* bias   = (const float*)d_in[10];
    float* ws   = (float*)d_ws;     // needs 434,176 bytes
    float* outp = (float*)d_out;

    precompute_kernel<<<265, 256, 0, stream>>>(ahs, goal, action, Wd, b_dist, Wg, w, a, ws);
    gat_row_kernel<<<256, 256, 0, stream>>>(ahs, ghs, b_gate, w, bias, ws, outp);
}

// Round 5
// 126.185 us; speedup vs baseline: 1.6344x; 1.2926x over previous
//
#include <hip/hip_runtime.h>
#include <hip/hip_bf16.h>

#define NN 256
#define HH 256

typedef __attribute__((ext_vector_type(8))) short short8;
typedef __attribute__((ext_vector_type(4))) float f32x4;

__device__ __forceinline__ ushort f2bf(float x) {
    __hip_bfloat16 h = __float2bfloat16(x);
    return *reinterpret_cast<ushort*>(&h);
}
template <int CTRL>
__device__ __forceinline__ float dpp_add(float x) {
    int y = __builtin_amdgcn_update_dpp(0, __float_as_int(x), CTRL, 0xF, 0xF, true);
    return x + __int_as_float(y);
}
__device__ __forceinline__ float red16(float v) {
    v = dpp_add<0xB1>(v);    // quad_perm(1,0,3,2)
    v = dpp_add<0x4E>(v);    // quad_perm(2,3,0,1)
    v = dpp_add<0x141>(v);   // row_half_mirror
    v = dpp_add<0x140>(v);   // row_mirror
    return v;
}

// Workspace (floats), total 632832 floats = 2,531,328 bytes:
//  P[256][64]@0  Q[256][64]@16384  T[256][256]@32768
//  WA[4][256]@98304  WB[4][256]@99328  WgT bf16[256][64]@100352 (4096 floats)
//  PV[2][4][256][256]@104448   (unnormalized v partials, [half][z][n][h])
//  ML[2][4][256][2]@628736     (m,l per [half][z][n])
#define WS_P   0
#define WS_Q   16384
#define WS_T   32768
#define WS_WA  98304
#define WS_WB  99328
#define WS_WGT 100352
#define WS_PV  104448
#define WS_ML  628736

__global__ __launch_bounds__(256) void precompute_kernel(
    const float* __restrict__ ahs, const float* __restrict__ goal,
    const float* __restrict__ action, const float* __restrict__ Wd,
    const float* __restrict__ b_dist, const float* __restrict__ Wg,
    const float* __restrict__ w, const float* __restrict__ a,
    float* __restrict__ ws)
{
    const int b = blockIdx.x;
    const int t = threadIdx.x;
    float* P  = ws + WS_P;
    float* Q  = ws + WS_Q;
    float* T  = ws + WS_T;
    float* WA = ws + WS_WA;
    float* WB = ws + WS_WB;
    ushort* WgT = (ushort*)(ws + WS_WGT);

    if (b < NN) {
        T[b*HH + t] = tanhf(ahs[b*HH + t]);
        if (t < 64) {
            float a0 = action[2*b], a1 = action[2*b+1];
            float g0 = goal[2*b],   g1 = goal[2*b+1];
            P[b*64 + t] = a0*Wd[0*64+t] + a1*Wd[1*64+t]
                        + g0*Wd[2*64+t] + g1*Wd[3*64+t] + b_dist[t];
            Q[b*64 + t] = a0*Wd[4*64+t] + a1*Wd[5*64+t]
                        + g0*Wd[6*64+t] + g1*Wd[7*64+t];
        }
    } else if (b < NN + 16) {
        // WA/WB via wave-cooperative coalesced row dots: one w pass for both.
        const int r    = b - NN;        // 0..15
        const int z    = r >> 2;
        const int rg   = r & 3;
        const int wid  = t >> 6;
        const int lane = t & 63;
        const int hbase = rg*64 + wid*16;
        const f32x4 aB = *(const f32x4*)(a + lane*4);         // a_flat[0:256]
        const f32x4 aA = *(const f32x4*)(a + HH + lane*4);    // a_flat[256:512]
#pragma unroll 4
        for (int rr = 0; rr < 16; ++rr) {
            const int h = hbase + rr;
            const f32x4 w4 = *(const f32x4*)(w + z*HH*HH + h*HH + lane*4);
            float dA = w4.x*aA.x + w4.y*aA.y + w4.z*aA.z + w4.w*aA.w;
            float dB = w4.x*aB.x + w4.y*aB.y + w4.z*aB.z + w4.w*aB.w;
#pragma unroll
            for (int off = 32; off; off >>= 1) {
                dA += __shfl_xor(dA, off);
                dB += __shfl_xor(dB, off);
            }
            if (lane == 0) { WA[z*HH + h] = dA; WB[z*HH + h] = dB; }
        }
    } else {
        // WgT[h][d] = bf16(Wg[d][h])  (B-operand layout for MFMA)
#pragma unroll 8
        for (int d = 0; d < 64; ++d) WgT[t*64 + d] = f2bf(Wg[d*HH + t]);
    }
}

// grid 512: block = (half, n). Each handles j in [half*128, half*128+128),
// 4 chunks of 32. Flash-style partial state; writes unnormalized v + (m,l).
__global__ __launch_bounds__(256) void gat_partial_kernel(
    const float* __restrict__ ahs, const float* __restrict__ ghs,
    const float* __restrict__ b_gate, float* __restrict__ ws)
{
    const int n    = blockIdx.x & 255;
    const int half = blockIdx.x >> 8;
    const int t    = threadIdx.x;
    const int wid  = t >> 6;
    const int lane = t & 63;
    const int quad = lane >> 4;
    const int l15  = lane & 15;
    const int n0   = wid * 64;

    const float* P  = ws + WS_P;
    const float* Q  = ws + WS_Q;
    const float* T  = ws + WS_T;
    const float* WA = ws + WS_WA;
    const float* WB = ws + WS_WB;
    const ushort* WgT = (const ushort*)(ws + WS_WGT);
    float* PV = ws + WS_PV;
    float* ML = ws + WS_ML;

    __shared__ ushort hidb[32][72];
    __shared__ __align__(16) float part[4][32][4];
    __shared__ __align__(16) float alpha_s[32][4];
    __shared__ __align__(16) float scl4[4];
    __shared__ float m_s[4], l_s[4], cz_s[4];
    __shared__ float vred[4][4][260];

    int hcol[4];
#pragma unroll
    for (int nt = 0; nt < 4; ++nt) hcol[nt] = n0 + nt*16 + l15;

    short8 bfrag[4][2];
    float  wa_reg[4][4];
    float  bgv[4];
#pragma unroll
    for (int nt = 0; nt < 4; ++nt) {
#pragma unroll
        for (int kh = 0; kh < 2; ++kh)
            bfrag[nt][kh] = *(const short8*)(WgT + hcol[nt]*64 + kh*32 + quad*8);
#pragma unroll
        for (int z = 0; z < 4; ++z) wa_reg[z][nt] = WA[z*HH + hcol[nt]];
        bgv[nt] = b_gate[hcol[nt]];
    }

    // vacc: [z][nt]; half 0 carries the k=0 self term on quad 0
    float vacc[4][4];
    {
        float av[4];
#pragma unroll
        for (int nt = 0; nt < 4; ++nt) av[nt] = ahs[n*HH + hcol[nt]];
#pragma unroll
        for (int z = 0; z < 4; ++z)
#pragma unroll
            for (int nt = 0; nt < 4; ++nt)
                vacc[z][nt] = (half == 0 && quad == 0) ? av[nt] : 0.f;
    }

    const int jj_own = t >> 3;
    const int db     = (t & 7) * 8;
    float pn[8];
#pragma unroll
    for (int i = 0; i < 8; ++i) pn[i] = P[n*64 + db + i];

    // init: cz for both halves; self-term softmax seed only in half 0
    {
        float pc = 0.f, ps = 0.f;
        for (int h = lane; h < HH; h += 64) {
            float av = ahs[n*HH + h];
            pc = fmaf(av, WB[wid*HH + h], pc);
            ps = fmaf(av, WA[wid*HH + h], ps);
        }
#pragma unroll
        for (int off = 32; off; off >>= 1) {
            pc += __shfl_xor(pc, off);
            ps += __shfl_xor(ps, off);
        }
        if (lane == 0) {
            cz_s[wid] = pc;
            if (half == 0) {
                float sc = pc + ps;
                float e0 = sc > 0.f ? sc : 0.2f * sc;
                m_s[wid] = e0;
                l_s[wid] = 1.0f;
            } else {
                m_s[wid] = -__builtin_inff();
                l_s[wid] = 0.0f;
            }
        }
    }
    __syncthreads();

    for (int cc = 0; cc < 4; ++cc) {
        const int j0 = half*128 + cc*32;

        // ---- T prefetch for this chunk (independent of MFMA path) ----
        float tval[2][4][4];
#pragma unroll
        for (int mt = 0; mt < 2; ++mt)
#pragma unroll
            for (int r = 0; r < 4; ++r) {
                const int jg = j0 + mt*16 + quad*4 + r;
#pragma unroll
                for (int nt = 0; nt < 4; ++nt)
                    tval[mt][nt][r] = T[jg*HH + hcol[nt]];
            }

        // ---- s1: hid chunk = relu(P[n]+Q[j]) -> bf16 LDS ----
        {
            const int j = j0 + jj_own;
            const float4 qa = *(const float4*)(Q + j*64 + db);
            const float4 qb = *(const float4*)(Q + j*64 + db + 4);
            ushort hv[8];
            hv[0] = f2bf(fmaxf(pn[0] + qa.x, 0.f));
            hv[1] = f2bf(fmaxf(pn[1] + qa.y, 0.f));
            hv[2] = f2bf(fmaxf(pn[2] + qa.z, 0.f));
            hv[3] = f2bf(fmaxf(pn[3] + qa.w, 0.f));
            hv[4] = f2bf(fmaxf(pn[4] + qb.x, 0.f));
            hv[5] = f2bf(fmaxf(pn[5] + qb.y, 0.f));
            hv[6] = f2bf(fmaxf(pn[6] + qb.z, 0.f));
            hv[7] = f2bf(fmaxf(pn[7] + qb.w, 0.f));
            *(short8*)&hidb[jj_own][db] = *(short8*)hv;
        }
        __syncthreads();   // B1

        // ---- s2: MFMA U = Hid @ Wg ----
        f32x4 acc[2][4];
#pragma unroll
        for (int mt = 0; mt < 2; ++mt)
#pragma unroll
            for (int nt = 0; nt < 4; ++nt) acc[mt][nt] = (f32x4){0.f,0.f,0.f,0.f};

        short8 afrag[2][2];
#pragma unroll
        for (int mt = 0; mt < 2; ++mt)
#pragma unroll
            for (int kh = 0; kh < 2; ++kh)
                afrag[mt][kh] = *(const short8*)&hidb[mt*16 + l15][kh*32 + quad*8];

#pragma unroll
        for (int mt = 0; mt < 2; ++mt)
#pragma unroll
            for (int nt = 0; nt < 4; ++nt) {
                acc[mt][nt] = __builtin_amdgcn_mfma_f32_16x16x32_bf16(
                    afrag[mt][0], bfrag[nt][0], acc[mt][nt], 0, 0, 0);
                acc[mt][nt] = __builtin_amdgcn_mfma_f32_16x16x32_bf16(
                    afrag[mt][1], bfrag[nt][1], acc[mt][nt], 0, 0, 0);
            }

        // epilogue: gate -> val (regs, T already resident), fused score partials
        float vals[2][4][4];
        float pp[4][2][4];
#pragma unroll
        for (int z = 0; z < 4; ++z)
#pragma unroll
            for (int mt = 0; mt < 2; ++mt)
#pragma unroll
                for (int r = 0; r < 4; ++r) pp[z][mt][r] = 0.f;

#pragma unroll
        for (int mt = 0; mt < 2; ++mt) {
#pragma unroll
            for (int r = 0; r < 4; ++r) {
                const int jg = j0 + mt*16 + quad*4 + r;
                const bool diag = (jg == n);
#pragma unroll
                for (int nt = 0; nt < 4; ++nt) {
                    float u = acc[mt][nt][r] + bgv[nt];
                    float val;
                    if (diag) {
                        val = ghs[n*HH + hcol[nt]];
                    } else {
                        float g = 1.0f / (1.0f + __expf(-u));
                        val = g * tval[mt][nt][r];
                    }
                    vals[mt][nt][r] = val;
                    pp[0][mt][r] = fmaf(val, wa_reg[0][nt], pp[0][mt][r]);
                    pp[1][mt][r] = fmaf(val, wa_reg[1][nt], pp[1][mt][r]);
                    pp[2][mt][r] = fmaf(val, wa_reg[2][nt], pp[2][mt][r]);
                    pp[3][mt][r] = fmaf(val, wa_reg[3][nt], pp[3][mt][r]);
                }
            }
        }
#pragma unroll
        for (int z = 0; z < 4; ++z)
#pragma unroll
            for (int mt = 0; mt < 2; ++mt)
#pragma unroll
                for (int r = 0; r < 4; ++r)
                    pp[z][mt][r] = red16(pp[z][mt][r]);
        if (l15 == 0) {
#pragma unroll
            for (int z = 0; z < 4; ++z)
#pragma unroll
                for (int mt = 0; mt < 2; ++mt)
#pragma unroll
                    for (int r = 0; r < 4; ++r)
                        part[z][mt*16 + quad*4 + r][wid] = pp[z][mt][r];
        }
        __syncthreads();   // B2

        // ---- s3: softmax update for head z=wid ----
        {
            const int jj = lane & 31;
            f32x4 pr = *(const f32x4*)&part[wid][jj][0];
            const bool act = lane < 32;
            float s = cz_s[wid] + ((pr.x + pr.y) + (pr.z + pr.w));
            float e = act ? (s > 0.f ? s : 0.2f * s) : -__builtin_inff();
            float mx = e;
#pragma unroll
            for (int off = 32; off; off >>= 1) mx = fmaxf(mx, __shfl_xor(mx, off));
            float m_old = m_s[wid];
            float m_new = fmaxf(m_old, mx);
            float at = act ? __expf(e - m_new) : 0.f;
            float ss = at;
#pragma unroll
            for (int off = 32; off; off >>= 1) ss += __shfl_xor(ss, off);
            if (act) alpha_s[jj][wid] = at;
            if (lane == 0) {
                float scale = __expf(m_old - m_new);   // expf(-inf)=0 handles half-1 seed
                scl4[wid] = scale;
                l_s[wid]  = l_s[wid] * scale + ss;
                m_s[wid]  = m_new;
            }
        }
        __syncthreads();   // B3

        // ---- s4: vacc update in registers ----
        {
            f32x4 scv = *(const f32x4*)&scl4[0];
            float s0 = scv.x, s1 = scv.y, s2 = scv.z, s3 = scv.w;
#pragma unroll
            for (int nt = 0; nt < 4; ++nt) {
                vacc[0][nt] *= s0; vacc[1][nt] *= s1;
                vacc[2][nt] *= s2; vacc[3][nt] *= s3;
            }
#pragma unroll
            for (int mt = 0; mt < 2; ++mt)
#pragma unroll
                for (int r = 0; r < 4; ++r) {
                    f32x4 al = *(const f32x4*)&alpha_s[mt*16 + quad*4 + r][0];
#pragma unroll
                    for (int nt = 0; nt < 4; ++nt) {
                        float v = vals[mt][nt][r];
                        vacc[0][nt] = fmaf(al.x, v, vacc[0][nt]);
                        vacc[1][nt] = fmaf(al.y, v, vacc[1][nt]);
                        vacc[2][nt] = fmaf(al.z, v, vacc[2][nt]);
                        vacc[3][nt] = fmaf(al.w, v, vacc[3][nt]);
                    }
                }
        }
        // safe without barrier: next chunk's part/alpha writes are behind B1'/B2'
    }

    // quad-reduce vacc via LDS, write unnormalized partials + (m,l)
#pragma unroll
    for (int z = 0; z < 4; ++z)
#pragma unroll
        for (int nt = 0; nt < 4; ++nt)
            vred[quad][z][hcol[nt]] = vacc[z][nt];
    __syncthreads();
#pragma unroll
    for (int z = 0; z < 4; ++z) {
        float s = (vred[0][z][t] + vred[1][z][t]) + (vred[2][z][t] + vred[3][z][t]);
        PV[((half*4 + z)*NN + n)*HH + t] = s;
    }
    if (lane == 0) {
        ML[((half*4 + wid)*NN + n)*2 + 0] = m_s[wid];
        ML[((half*4 + wid)*NN + n)*2 + 1] = l_s[wid];
    }
}

// grid 256 (one per n): merge halves, normalize, project through w, relu+bias.
__global__ __launch_bounds__(256) void gat_combine_kernel(
    const float* __restrict__ w, const float* __restrict__ bias,
    const float* __restrict__ ws, float* __restrict__ out)
{
    const int n = blockIdx.x;
    const int t = threadIdx.x;
    const float* PV = ws + WS_PV;
    const float* ML = ws + WS_ML;

    __shared__ float vfin[4][256];

#pragma unroll
    for (int z = 0; z < 4; ++z) {
        float mA = ML[((0*4 + z)*NN + n)*2 + 0];
        float lA = ML[((0*4 + z)*NN + n)*2 + 1];
        float mB = ML[((1*4 + z)*NN + n)*2 + 0];
        float lB = ML[((1*4 + z)*NN + n)*2 + 1];
        float m  = fmaxf(mA, mB);
        float sA = __expf(mA - m);
        float sB = __expf(mB - m);
        float inv = 1.0f / (lA*sA + lB*sB);     // lA >= 1 (self term) -> denom > 0
        float vA = PV[((0*4 + z)*NN + n)*HH + t];
        float vB = PV[((1*4 + z)*NN + n)*HH + t];
        vfin[z][t] = (vA*sA + vB*sB) * inv;
    }
    __syncthreads();

    float res = 0.f;
#pragma unroll
    for (int z = 0; z < 4; ++z) {
        const float* wz = w + z*HH*HH + t;    // column f=t, stride HH (lane-coalesced)
        float a0 = 0.f, a1 = 0.f;
        for (int h = 0; h < HH; h += 8) {
            float l0 = wz[(h+0)*HH], l1 = wz[(h+1)*HH];
            float l2 = wz[(h+2)*HH], l3 = wz[(h+3)*HH];
            float l4 = wz[(h+4)*HH], l5 = wz[(h+5)*HH];
            float l6 = wz[(h+6)*HH], l7 = wz[(h+7)*HH];
            f32x4 v0 = *(const f32x4*)&vfin[z][h];
            f32x4 v1 = *(const f32x4*)&vfin[z][h+4];
            a0 = fmaf(l0, v0.x, a0); a1 = fmaf(l1, v0.y, a1);
            a0 = fmaf(l2, v0.z, a0); a1 = fmaf(l3, v0.w, a1);
            a0 = fmaf(l4, v1.x, a0); a1 = fmaf(l5, v1.y, a1);
            a0 = fmaf(l6, v1.z, a0); a1 = fmaf(l7, v1.w, a1);
        }
        res += a0 + a1;
    }
    res = fmaxf(res * 0.25f, 0.f) + bias[t];
    out[n*HH + t] = res;
}

extern "C" void kernel_launch(void* const* d_in, const int* in_sizes, int n_in,
                              void* d_out, int out_size, void* d_ws, size_t ws_size,
                              hipStream_t stream)
{
    const float* ahs    = (const float*)d_in[0];
    const float* ghs    = (const float*)d_in[1];
    const float* goal   = (const float*)d_in[2];
    const float* action = (const float*)d_in[3];
    const float* Wd     = (const float*)d_in[4];
    const float* b_dist = (const float*)d_in[5];
    const float* Wg     = (const float*)d_in[6];
    const float* b_gate = (const float*)d_in[7];
    const float* w      = (const float*)d_in[8];
    const float* a      = (const float*)d_in[9];
    const float* bias   = (const float*)d_in[10];
    float* ws   = (float*)d_ws;     // needs 2,531,328 bytes
    float* outp = (float*)d_out;

    precompute_kernel<<<273, 256, 0, stream>>>(ahs, goal, action, Wd, b_dist, Wg, w, a, ws);
    gat_partial_kernel<<<512, 256, 0, stream>>>(ahs, ghs, b_gate, ws);
    gat_combine_kernel<<<256, 256, 0, stream>>>(w, bias, ws, outp);
}